// Round 1
// baseline (3235.813 us; speedup 1.0000x reference)
//
#include <hip/hip_runtime.h>
#include <math.h>

#define NEG32 -1e32f

// LDS float-offsets for the big aliased pool.
// emb [16][132]; three [16][258] slots A/B/C reused across phases; attn [8][16][16].
#define OFF_E 0
#define OFF_A 2112   // q   -> ctx    -> h2/dynamic
#define OFF_B 6240   // k   -> dyn_in -> sta1
#define OFF_C 10368  // v   -> h1     -> static
#define OFF_T 14496  // attn scores [8][16][16] = 2048
#define POOL_SZ 16544

// out[l][tid] += sum_d sIn[l][d] * W[tid][d], K-wide rows, float4 weight loads.
template <int K, int STRIDE>
__device__ __forceinline__ void mat16(const float* __restrict__ W, int tid,
                                      const float* sIn, float* acc) {
  const float4* W4 = (const float4*)(W + (size_t)tid * K);
#pragma unroll 4
  for (int d4 = 0; d4 < K / 4; ++d4) {
    float4 w = W4[d4];
    const int d = d4 * 4;
#pragma unroll
    for (int l = 0; l < 16; ++l) {
      const float* r = sIn + l * STRIDE + d;
      float a = acc[l];
      a = fmaf(r[0], w.x, a);
      a = fmaf(r[1], w.y, a);
      a = fmaf(r[2], w.z, a);
      a = fmaf(r[3], w.w, a);
      acc[l] = a;
    }
  }
}

__global__ __launch_bounds__(256, 2) void classifier_kernel(
    const int* __restrict__ x, const float* __restrict__ node_emb,
    const float* __restrict__ ln1_g, const float* __restrict__ ln1_b,
    const float* __restrict__ ln2_g, const float* __restrict__ ln2_b,
    const float* __restrict__ ln3_g, const float* __restrict__ ln3_b,
    const float* __restrict__ Wq, const float* __restrict__ Wk,
    const float* __restrict__ Wv, const float* __restrict__ Wfc1,
    const float* __restrict__ p1_w1, const float* __restrict__ p1_b1,
    const float* __restrict__ p1_w2, const float* __restrict__ p1_b2,
    const float* __restrict__ p1_lng, const float* __restrict__ p1_lnb,
    const float* __restrict__ p2_w1, const float* __restrict__ p2_b1,
    const float* __restrict__ p2_w2, const float* __restrict__ p2_b2,
    const float* __restrict__ lnc1_g, const float* __restrict__ lnc1_b,
    const float* __restrict__ lnc2_g, const float* __restrict__ lnc2_b,
    const float* __restrict__ Wcls, const float* __restrict__ bcls,
    float* __restrict__ out) {
  __shared__ float sm[POOL_SZ];
  __shared__ int s_xi[16];
  __shared__ float s_npm[16], s_mean[16], s_rstd[16], s_prob[16];

  const int tid = threadIdx.x;
  const int b = blockIdx.x;

  float* s_emb = sm + OFF_E;  // stride 132
  float* sA = sm + OFF_A;     // stride 258
  float* sB = sm + OFF_B;
  float* sC = sm + OFF_C;
  float* s_att = sm + OFF_T;

  // ---------- P1: token ids, npm, embedding gather ----------
  if (tid < 16) {
    int xi = x[b * 16 + tid];
    s_xi[tid] = xi;
    s_npm[tid] = (xi != 0) ? 1.0f : 0.0f;
  }
  __syncthreads();
#pragma unroll
  for (int j = 0; j < 8; ++j) {
    int e = j * 256 + tid;
    int l = e >> 7, d = e & 127;
    s_emb[l * 132 + d] = node_emb[(size_t)s_xi[l] * 128 + d];
  }
  __syncthreads();

  // ---------- LN stats over emb rows (shared basis for ln1/ln2/ln3) ----------
  {
    const int r = tid >> 4, s = tid & 15;
    float sum = 0.f, sq = 0.f;
#pragma unroll
    for (int k = 0; k < 8; ++k) {
      float v = s_emb[r * 132 + s + k * 16];
      sum += v;
      sq += v * v;
    }
#pragma unroll
    for (int off = 8; off; off >>= 1) {
      sum += __shfl_xor(sum, off);
      sq += __shfl_xor(sq, off);
    }
    if (s == 0) {
      float m = sum * (1.f / 128.f);
      float var = sq * (1.f / 128.f) - m * m;
      s_mean[r] = m;
      s_rstd[r] = rsqrtf(var + 1e-5f);
    }
  }
  __syncthreads();

  // ---------- P3: q/k/v projections with LN(g,b) folded into epilogue ----------
  // input = ((emb-m)*rstd)*g + b  =>  q[o] = rstd*(sum emb*(g*W) - m*sum(g*W)) + sum(b*W)
  {
    const float* Ws[3] = {Wq, Wk, Wv};
    const float* gs[3] = {ln1_g, ln2_g, ln3_g};
    const float* bs[3] = {ln1_b, ln2_b, ln3_b};
    float* outs[3] = {sA, sB, sC};
#pragma unroll
    for (int p = 0; p < 3; ++p) {
      const float4* W4 = (const float4*)(Ws[p] + (size_t)tid * 128);
      const float4* g4 = (const float4*)gs[p];
      const float4* b4 = (const float4*)bs[p];
      float acc[16];
#pragma unroll
      for (int l = 0; l < 16; ++l) acc[l] = 0.f;
      float sgw = 0.f, sbw = 0.f;
#pragma unroll 4
      for (int d4 = 0; d4 < 32; ++d4) {
        float4 w = W4[d4];
        float4 g = g4[d4];
        float4 bb = b4[d4];
        float gw0 = w.x * g.x, gw1 = w.y * g.y, gw2 = w.z * g.z, gw3 = w.w * g.w;
        sgw += gw0 + gw1 + gw2 + gw3;
        sbw += w.x * bb.x + w.y * bb.y + w.z * bb.z + w.w * bb.w;
        const int d = d4 * 4;
#pragma unroll
        for (int l = 0; l < 16; ++l) {
          const float* r = s_emb + l * 132 + d;
          float a = acc[l];
          a = fmaf(r[0], gw0, a);
          a = fmaf(r[1], gw1, a);
          a = fmaf(r[2], gw2, a);
          a = fmaf(r[3], gw3, a);
          acc[l] = a;
        }
      }
      float* o = outs[p];
#pragma unroll
      for (int l = 0; l < 16; ++l)
        o[l * 258 + tid] = s_rstd[l] * (acc[l] - s_mean[l] * sgw) + sbw;
    }
  }
  __syncthreads();

  // ---------- P4: scores + diag mask + softmax ----------
  {
    const int l = tid >> 4, m = tid & 15;
#pragma unroll
    for (int h = 0; h < 8; ++h) {
      const float* qr = sA + l * 258 + h * 32;
      const float* kr = sB + m * 258 + h * 32;
      float s = 0.f;
#pragma unroll
      for (int d = 0; d < 32; ++d) s = fmaf(qr[d], kr[d], s);
      s *= 0.17677669529663687f;  // 1/sqrt(32)
      if (l == m) s = NEG32;
      s_att[h * 256 + l * 16 + m] = s;
    }
  }
  __syncthreads();
  if (tid < 128) {
    const int h = tid >> 4, l = tid & 15;
    float* row = s_att + h * 256 + l * 16;
    float mx = row[0];
#pragma unroll
    for (int m = 1; m < 16; ++m) mx = fmaxf(mx, row[m]);
    float e[16], sum = 0.f;
#pragma unroll
    for (int m = 0; m < 16; ++m) {
      e[m] = __expf(row[m] - mx);
      sum += e[m];
    }
    float inv = 1.f / sum;
#pragma unroll
    for (int m = 0; m < 16; ++m) row[m] = e[m] * inv;
  }
  __syncthreads();

  // ---------- P5: ctx = attn @ v  (write into A; q,k dead) ----------
  {
    const int h = tid >> 5;
    float acc[16];
#pragma unroll
    for (int l = 0; l < 16; ++l) acc[l] = 0.f;
#pragma unroll
    for (int m = 0; m < 16; ++m) {
      float vv = sC[m * 258 + tid];
      const float* ar = s_att + h * 256 + m;
#pragma unroll
      for (int l = 0; l < 16; ++l) acc[l] = fmaf(ar[l * 16], vv, acc[l]);
    }
    __syncthreads();  // ensure all reads of q-slot done before overwrite (paranoia: q dead already)
#pragma unroll
    for (int l = 0; l < 16; ++l) sA[l * 258 + tid] = acc[l];
  }
  __syncthreads();

  // ---------- P6: dyn_in = (ctx @ Wfc1^T) * npm  -> B ----------
  {
    float acc[16];
#pragma unroll
    for (int l = 0; l < 16; ++l) acc[l] = 0.f;
    mat16<256, 258>(Wfc1, tid, sA, acc);
    __syncthreads();
#pragma unroll
    for (int l = 0; l < 16; ++l) sB[l * 258 + tid] = acc[l] * s_npm[l];
  }
  __syncthreads();

  // ---------- P7: h1 = tanh(dyn_in @ p1_w1^T + b1) -> C ----------
  {
    float acc[16];
#pragma unroll
    for (int l = 0; l < 16; ++l) acc[l] = 0.f;
    mat16<256, 258>(p1_w1, tid, sB, acc);
    const float bias = p1_b1[tid];
    __syncthreads();
#pragma unroll
    for (int l = 0; l < 16; ++l) sC[l * 258 + tid] = tanhf(acc[l] + bias);
  }
  __syncthreads();

  // ---------- P8: h2 = h1 @ p1_w2^T + b2 + dyn_in -> A; then LN*npm in place ----------
  {
    float acc[16];
#pragma unroll
    for (int l = 0; l < 16; ++l) acc[l] = 0.f;
    mat16<256, 258>(p1_w2, tid, sC, acc);
    const float bias = p1_b2[tid];
#pragma unroll
    for (int l = 0; l < 16; ++l) acc[l] += bias + sB[l * 258 + tid];
    __syncthreads();
#pragma unroll
    for (int l = 0; l < 16; ++l) sA[l * 258 + tid] = acc[l];
  }
  __syncthreads();
  {
    const int r = tid >> 4, s = tid & 15;
    float vals[16], sum = 0.f, sq = 0.f;
#pragma unroll
    for (int k = 0; k < 16; ++k) {
      float v = sA[r * 258 + s + k * 16];
      vals[k] = v;
      sum += v;
      sq += v * v;
    }
#pragma unroll
    for (int off = 8; off; off >>= 1) {
      sum += __shfl_xor(sum, off);
      sq += __shfl_xor(sq, off);
    }
    const float m = sum * (1.f / 256.f);
    const float rstd = rsqrtf(sq * (1.f / 256.f) - m * m + 1e-5f);
    const float np = s_npm[r];
#pragma unroll
    for (int k = 0; k < 16; ++k) {
      const int c = s + k * 16;
      sA[r * 258 + c] = ((vals[k] - m) * rstd * p1_lng[c] + p1_lnb[c]) * np;
    }
  }
  __syncthreads();

  // ---------- P9: sta1 = tanh((emb*npm) @ p2_w1^T + b1) -> B ----------
  {
    float acc[16];
#pragma unroll
    for (int l = 0; l < 16; ++l) acc[l] = 0.f;
    mat16<128, 132>(p2_w1, tid, s_emb, acc);
    const float bias = p2_b1[tid];
    __syncthreads();
#pragma unroll
    for (int l = 0; l < 16; ++l) sB[l * 258 + tid] = tanhf(s_npm[l] * acc[l] + bias);
  }
  __syncthreads();

  // ---------- P10: static = (sta1 @ p2_w2^T + b2) * npm -> C ----------
  {
    float acc[16];
#pragma unroll
    for (int l = 0; l < 16; ++l) acc[l] = 0.f;
    mat16<256, 258>(p2_w2, tid, sB, acc);
    const float bias = p2_b2[tid];
    __syncthreads();
#pragma unroll
    for (int l = 0; l < 16; ++l) sC[l * 258 + tid] = (acc[l] + bias) * s_npm[l];
  }
  __syncthreads();

  // ---------- P11: dyn=LN(dynamic,lnc1), sta=LN(static,lnc2), classifier ----------
  {
    const int r = tid >> 4, s = tid & 15;
    float dv[16], sv[16];
    float dsum = 0.f, dsq = 0.f, ssum = 0.f, ssq = 0.f;
#pragma unroll
    for (int k = 0; k < 16; ++k) {
      float d = sA[r * 258 + s + k * 16];
      float t = sC[r * 258 + s + k * 16];
      dv[k] = d;
      sv[k] = t;
      dsum += d;
      dsq += d * d;
      ssum += t;
      ssq += t * t;
    }
#pragma unroll
    for (int off = 8; off; off >>= 1) {
      dsum += __shfl_xor(dsum, off);
      dsq += __shfl_xor(dsq, off);
      ssum += __shfl_xor(ssum, off);
      ssq += __shfl_xor(ssq, off);
    }
    const float mD = dsum * (1.f / 256.f);
    const float rD = rsqrtf(dsq * (1.f / 256.f) - mD * mD + 1e-5f);
    const float mS = ssum * (1.f / 256.f);
    const float rS = rsqrtf(ssq * (1.f / 256.f) - mS * mS + 1e-5f);
    float part = 0.f;
#pragma unroll
    for (int k = 0; k < 16; ++k) {
      const int c = s + k * 16;
      float dn = (dv[k] - mD) * rD * lnc1_g[c] + lnc1_b[c];
      float st = (sv[k] - mS) * rS * lnc2_g[c] + lnc2_b[c];
      float df = dn - st;
      part = fmaf(df * df, Wcls[c], part);
    }
#pragma unroll
    for (int off = 8; off; off >>= 1) part += __shfl_xor(part, off);
    if (s == 0) {
      float logit = part + bcls[0];
      float p = 1.f / (1.f + __expf(-logit));
      s_prob[r] = p * s_npm[r];
    }
  }
  __syncthreads();
  if (tid == 0) {
    float ps = 0.f, ns = 0.f;
#pragma unroll
    for (int l = 0; l < 16; ++l) {
      ps += s_prob[l];
      ns += s_npm[l];
    }
    out[b] = ps / ns;
  }
}

extern "C" void kernel_launch(void* const* d_in, const int* in_sizes, int n_in,
                              void* d_out, int out_size, void* d_ws, size_t ws_size,
                              hipStream_t stream) {
  const int* x = (const int*)d_in[0];
  const float* node_emb = (const float*)d_in[1];
  const float* ln1_g = (const float*)d_in[2];
  const float* ln1_b = (const float*)d_in[3];
  const float* ln2_g = (const float*)d_in[4];
  const float* ln2_b = (const float*)d_in[5];
  const float* ln3_g = (const float*)d_in[6];
  const float* ln3_b = (const float*)d_in[7];
  const float* Wq = (const float*)d_in[8];
  const float* Wk = (const float*)d_in[9];
  const float* Wv = (const float*)d_in[10];
  const float* Wfc1 = (const float*)d_in[11];
  const float* p1_w1 = (const float*)d_in[12];
  const float* p1_b1 = (const float*)d_in[13];
  const float* p1_w2 = (const float*)d_in[14];
  const float* p1_b2 = (const float*)d_in[15];
  const float* p1_lng = (const float*)d_in[16];
  const float* p1_lnb = (const float*)d_in[17];
  const float* p2_w1 = (const float*)d_in[18];
  const float* p2_b1 = (const float*)d_in[19];
  const float* p2_w2 = (const float*)d_in[20];
  const float* p2_b2 = (const float*)d_in[21];
  const float* lnc1_g = (const float*)d_in[22];
  const float* lnc1_b = (const float*)d_in[23];
  const float* lnc2_g = (const float*)d_in[24];
  const float* lnc2_b = (const float*)d_in[25];
  const float* Wcls = (const float*)d_in[26];
  const float* bcls = (const float*)d_in[27];

  const int B = in_sizes[0] / 16;
  classifier_kernel<<<B, 256, 0, stream>>>(
      x, node_emb, ln1_g, ln1_b, ln2_g, ln2_b, ln3_g, ln3_b, Wq, Wk, Wv, Wfc1,
      p1_w1, p1_b1, p1_w2, p1_b2, p1_lng, p1_lnb, p2_w1, p2_b1, p2_w2, p2_b2,
      lnc1_g, lnc1_b, lnc2_g, lnc2_b, Wcls, bcls, (float*)d_out);
}

// Round 2
// 772.821 us; speedup vs baseline: 4.1870x; 4.1870x over previous
//
#include <hip/hip_runtime.h>
#include <math.h>

typedef unsigned short u16;
typedef __bf16 bf16x8 __attribute__((ext_vector_type(8)));
typedef u16 u16x8 __attribute__((ext_vector_type(8)));
typedef float f32x4 __attribute__((ext_vector_type(4)));

// ---- LDS pool offsets (u16 units) ----
// E: emb [32][136]            (gather -> QKV)   ; later ATT [16 pairs][16][16], later red f32
// S1: ST1_hi -> Q -> CTX_hi -> H1_hi   [32][264]
// S2: ST1_lo -> K -> CTX_lo -> H1_lo   [32][264]
// S3: V -> DIN                         [32][264]
#define E_O 0
#define E_S 136
#define S1_O 4352
#define S2_O 12800
#define S3_O 21248
#define ACT_S 264
#define ATT_O 0
#define POOL_U 29696

__device__ __forceinline__ u16 bfb(float f) {
  unsigned u = __builtin_bit_cast(unsigned, f);
  unsigned r = u + 0x7fffu + ((u >> 16) & 1u);
  return (u16)(r >> 16);
}
__device__ __forceinline__ float b2f(u16 h) {
  return __builtin_bit_cast(float, (unsigned)h << 16);
}
__device__ __forceinline__ float tanh_f(float x) {
  float e = __expf(2.f * x);
  return 1.f - 2.f / (e + 1.f);
}

// out[l][n] += sum_k act[l][k] * W[n][k]; A rows = lane&15, k = (lane>>4)*8+i (m89 convention)
template <int K, int SS>
__device__ __forceinline__ void mm_acc(const u16* sA, const u16* __restrict__ W,
                                       f32x4 acc[2][4], int wid, int g, int sr) {
  const int ko = g * 8;
#pragma unroll
  for (int k0 = 0; k0 < K; k0 += 32) {
    bf16x8 a0 = *(const bf16x8*)(sA + sr * SS + k0 + ko);
    bf16x8 a1 = *(const bf16x8*)(sA + (16 + sr) * SS + k0 + ko);
#pragma unroll
    for (int n = 0; n < 4; ++n) {
      bf16x8 bw = *(const bf16x8*)(W + (size_t)(wid * 64 + n * 16 + sr) * K + k0 + ko);
      acc[0][n] = __builtin_amdgcn_mfma_f32_16x16x32_bf16(a0, bw, acc[0][n], 0, 0, 0);
      acc[1][n] = __builtin_amdgcn_mfma_f32_16x16x32_bf16(a1, bw, acc[1][n], 0, 0, 0);
    }
  }
}

__global__ __launch_bounds__(256) void fused_kernel(
    const int* __restrict__ x, const float* __restrict__ node_emb,
    const u16* __restrict__ wq, const u16* __restrict__ wk, const u16* __restrict__ wv,
    const u16* __restrict__ wfc1, const u16* __restrict__ w11, const u16* __restrict__ w12,
    const u16* __restrict__ w21, const u16* __restrict__ w22,
    const float* __restrict__ aux,
    const float* __restrict__ p1_b1, const float* __restrict__ p1_b2,
    const float* __restrict__ p1_lng, const float* __restrict__ p1_lnb,
    const float* __restrict__ p2_b1, const float* __restrict__ p2_b2,
    const float* __restrict__ lnc1_g, const float* __restrict__ lnc1_b,
    const float* __restrict__ lnc2_g, const float* __restrict__ lnc2_b,
    const float* __restrict__ Wcls, const float* __restrict__ bcls,
    float* __restrict__ out) {
  __shared__ __align__(16) u16 pool[POOL_U];
  __shared__ int s_xi[32];
  __shared__ float s_npm[32], s_mu[32], s_rs[32];
  __shared__ float s_a[32], s_b[32], s_c[32], s_d[32];
  __shared__ float s_prob[32];

  const int tid = threadIdx.x;
  const int wid = tid >> 6, lane = tid & 63;
  const int g = lane >> 4, sr = lane & 15;
  const int b0 = blockIdx.x * 2;

  if (tid < 32) {
    int xi = x[b0 * 16 + tid];
    s_xi[tid] = xi;
    s_npm[tid] = (xi != 0) ? 1.f : 0.f;
  }
  __syncthreads();

  // ---- gather emb (fp32 -> bf16 LDS) + LN stats from fp32 values ----
  {
    const int row = tid >> 3, j = tid & 7;
    const float4* src = (const float4*)(node_emb + (size_t)s_xi[row] * 128 + j * 16);
    u16* dst = pool + E_O + row * E_S + j * 16;
    float su = 0.f, sq = 0.f;
#pragma unroll
    for (int q4 = 0; q4 < 4; ++q4) {
      float4 v = src[q4];
      su += v.x + v.y + v.z + v.w;
      sq += v.x * v.x + v.y * v.y + v.z * v.z + v.w * v.w;
      dst[q4 * 4 + 0] = bfb(v.x);
      dst[q4 * 4 + 1] = bfb(v.y);
      dst[q4 * 4 + 2] = bfb(v.z);
      dst[q4 * 4 + 3] = bfb(v.w);
    }
#pragma unroll
    for (int o = 1; o < 8; o <<= 1) {
      su += __shfl_xor(su, o);
      sq += __shfl_xor(sq, o);
    }
    if (j == 0) {
      float mu = su * (1.f / 128.f);
      s_mu[row] = mu;
      s_rs[row] = rsqrtf(sq * (1.f / 128.f) - mu * mu + 1e-5f);
    }
  }
  __syncthreads();

  // ---- P9: ST1 = tanh(npm*(emb @ p2w1^T) + b1) -> S1(hi)/S2(lo) ----
  {
    f32x4 acc[2][4] = {};
    mm_acc<128, E_S>(pool + E_O, w21, acc, wid, g, sr);
#pragma unroll
    for (int m = 0; m < 2; ++m)
#pragma unroll
      for (int n = 0; n < 4; ++n)
#pragma unroll
        for (int i = 0; i < 4; ++i) {
          int row = m * 16 + g * 4 + i, col = wid * 64 + n * 16 + sr;
          float v = tanh_f(s_npm[row] * acc[m][n][i] + p2_b1[col]);
          u16 hi = bfb(v);
          pool[S1_O + row * ACT_S + col] = hi;
          pool[S2_O + row * ACT_S + col] = bfb(v - b2f(hi));
        }
  }
  __syncthreads();

  // ---- P10: static = (ST1 @ p2w2^T + b2)*npm -> kept in regs (sacc) ----
  f32x4 sacc[2][4] = {};
  mm_acc<256, ACT_S>(pool + S1_O, w22, sacc, wid, g, sr);
  mm_acc<256, ACT_S>(pool + S2_O, w22, sacc, wid, g, sr);
#pragma unroll
  for (int m = 0; m < 2; ++m)
#pragma unroll
    for (int n = 0; n < 4; ++n)
#pragma unroll
      for (int i = 0; i < 4; ++i) {
        int row = m * 16 + g * 4 + i, col = wid * 64 + n * 16 + sr;
        sacc[m][n][i] = (sacc[m][n][i] + p2_b2[col]) * s_npm[row];
      }
  __syncthreads();  // ST1 reads complete before Q/K overwrite S1/S2

  // ---- QKV: LN folded via pre-scaled weights + (G,B) epilogue vectors ----
  {
#pragma unroll
    for (int p = 0; p < 3; ++p) {
      const u16* W = (p == 0) ? wq : (p == 1) ? wk : wv;
      const int dsto = (p == 0) ? S1_O : (p == 1) ? S2_O : S3_O;
      const float* G = aux + p * 512;
      const float* Bv = aux + p * 512 + 256;
      f32x4 acc[2][4] = {};
      mm_acc<128, E_S>(pool + E_O, W, acc, wid, g, sr);
#pragma unroll
      for (int m = 0; m < 2; ++m)
#pragma unroll
        for (int n = 0; n < 4; ++n)
#pragma unroll
          for (int i = 0; i < 4; ++i) {
            int row = m * 16 + g * 4 + i, col = wid * 64 + n * 16 + sr;
            float v = s_rs[row] * (acc[m][n][i] - s_mu[row] * G[col]) + Bv[col];
            pool[dsto + row * ACT_S + col] = bfb(v);
          }
    }
  }
  __syncthreads();

  // ---- scores (MFMA, K=32) + diag mask + softmax -> ATT bf16 [pair][l][m] ----
  {
#pragma unroll
    for (int pi = 0; pi < 4; ++pi) {
      int pair = wid * 4 + pi, pb = pair >> 3, h = pair & 7;
      bf16x8 qa = *(const bf16x8*)(pool + S1_O + (pb * 16 + sr) * ACT_S + h * 32 + g * 8);
      bf16x8 kb = *(const bf16x8*)(pool + S2_O + (pb * 16 + sr) * ACT_S + h * 32 + g * 8);
      f32x4 z = {};
      f32x4 sc = __builtin_amdgcn_mfma_f32_16x16x32_bf16(qa, kb, z, 0, 0, 0);
#pragma unroll
      for (int i = 0; i < 4; ++i) {
        int l = g * 4 + i;
        float v = sc[i] * 0.17677669529663687f;
        if (sr == l) v = -3.0e38f;
        float mx = v;
#pragma unroll
        for (int o = 1; o < 16; o <<= 1) mx = fmaxf(mx, __shfl_xor(mx, o));
        float e = (sr == l) ? 0.f : __expf(v - mx);
        float s = e;
#pragma unroll
        for (int o = 1; o < 16; o <<= 1) s += __shfl_xor(s, o);
        pool[ATT_O + pair * 256 + l * 16 + sr] = bfb(e / s);
      }
    }
  }
  __syncthreads();

  // ---- PV: ctx = attn @ v (K=16 padded to 32) -> CTX hi/lo (S1/S2) ----
  {
#pragma unroll
    for (int pi = 0; pi < 4; ++pi) {
      int pair = wid * 4 + pi, pb = pair >> 3, h = pair & 7;
      u16x8 ta = {};
      if (g < 2) ta = *(const u16x8*)(pool + ATT_O + pair * 256 + sr * 16 + g * 8);
      bf16x8 pa = __builtin_bit_cast(bf16x8, ta);
#pragma unroll
      for (int dt = 0; dt < 2; ++dt) {
        int dcol = h * 32 + dt * 16 + sr;
        u16x8 tv = {};
        if (g < 2) {
          const u16* vp = pool + S3_O + (pb * 16 + g * 8) * ACT_S + dcol;
#pragma unroll
          for (int ii = 0; ii < 8; ++ii) tv[ii] = vp[ii * ACT_S];
        }
        bf16x8 vb = __builtin_bit_cast(bf16x8, tv);
        f32x4 z = {};
        f32x4 c = __builtin_amdgcn_mfma_f32_16x16x32_bf16(pa, vb, z, 0, 0, 0);
#pragma unroll
        for (int i = 0; i < 4; ++i) {
          int row = pb * 16 + g * 4 + i;
          u16 hi = bfb(c[i]);
          pool[S1_O + row * ACT_S + dcol] = hi;
          pool[S2_O + row * ACT_S + dcol] = bfb(c[i] - b2f(hi));
        }
      }
    }
  }
  __syncthreads();

  // ---- P6: dyn_in = (ctx @ Wfc1^T)*npm -> regs (rin, exact residual) + DIN bf16 (S3) ----
  f32x4 rin[2][4] = {};
  mm_acc<256, ACT_S>(pool + S1_O, wfc1, rin, wid, g, sr);
  mm_acc<256, ACT_S>(pool + S2_O, wfc1, rin, wid, g, sr);
#pragma unroll
  for (int m = 0; m < 2; ++m)
#pragma unroll
    for (int n = 0; n < 4; ++n)
#pragma unroll
      for (int i = 0; i < 4; ++i) {
        int row = m * 16 + g * 4 + i, col = wid * 64 + n * 16 + sr;
        rin[m][n][i] *= s_npm[row];
        pool[S3_O + row * ACT_S + col] = bfb(rin[m][n][i]);
      }
  __syncthreads();

  // ---- P7: h1 = tanh(dyn_in @ p1w1^T + b1) -> H1 hi/lo (S1/S2) ----
  {
    f32x4 acc[2][4] = {};
    mm_acc<256, ACT_S>(pool + S3_O, w11, acc, wid, g, sr);
#pragma unroll
    for (int m = 0; m < 2; ++m)
#pragma unroll
      for (int n = 0; n < 4; ++n)
#pragma unroll
        for (int i = 0; i < 4; ++i) {
          int row = m * 16 + g * 4 + i, col = wid * 64 + n * 16 + sr;
          float v = tanh_f(acc[m][n][i] + p1_b1[col]);
          u16 hi = bfb(v);
          pool[S1_O + row * ACT_S + col] = hi;
          pool[S2_O + row * ACT_S + col] = bfb(v - b2f(hi));
        }
  }
  __syncthreads();

  // ---- P8: h2 = h1@p1w2^T + b2 + dyn_in(reg); LN(p1_ln)*npm -> dacc regs ----
  f32x4 dacc[2][4] = {};
  mm_acc<256, ACT_S>(pool + S1_O, w12, dacc, wid, g, sr);
  mm_acc<256, ACT_S>(pool + S2_O, w12, dacc, wid, g, sr);
#pragma unroll
  for (int m = 0; m < 2; ++m)
#pragma unroll
    for (int n = 0; n < 4; ++n)
#pragma unroll
      for (int i = 0; i < 4; ++i) {
        int col = wid * 64 + n * 16 + sr;
        dacc[m][n][i] += p1_b2[col] + rin[m][n][i];
      }
  {
    float* red = (float*)pool;
    float ps[2][4], pq[2][4];
#pragma unroll
    for (int m = 0; m < 2; ++m)
#pragma unroll
      for (int i = 0; i < 4; ++i) {
        float a = 0.f, b = 0.f;
#pragma unroll
        for (int n = 0; n < 4; ++n) {
          float v = dacc[m][n][i];
          a += v;
          b += v * v;
        }
#pragma unroll
        for (int o = 1; o < 16; o <<= 1) {
          a += __shfl_xor(a, o);
          b += __shfl_xor(b, o);
        }
        ps[m][i] = a;
        pq[m][i] = b;
      }
    if (sr == 0)
#pragma unroll
      for (int m = 0; m < 2; ++m)
#pragma unroll
        for (int i = 0; i < 4; ++i) {
          int row = m * 16 + g * 4 + i;
          red[row * 4 + wid] = ps[m][i];
          red[128 + row * 4 + wid] = pq[m][i];
        }
    __syncthreads();
    if (tid < 32) {
      float a = 0.f, b = 0.f;
#pragma unroll
      for (int w = 0; w < 4; ++w) {
        a += red[tid * 4 + w];
        b += red[128 + tid * 4 + w];
      }
      float mu = a * (1.f / 256.f);
      s_a[tid] = mu;
      s_b[tid] = rsqrtf(b * (1.f / 256.f) - mu * mu + 1e-5f);
    }
    __syncthreads();
#pragma unroll
    for (int m = 0; m < 2; ++m)
#pragma unroll
      for (int n = 0; n < 4; ++n)
#pragma unroll
        for (int i = 0; i < 4; ++i) {
          int row = m * 16 + g * 4 + i, col = wid * 64 + n * 16 + sr;
          dacc[m][n][i] =
              ((dacc[m][n][i] - s_a[row]) * s_b[row] * p1_lng[col] + p1_lnb[col]) * s_npm[row];
        }
  }

  // ---- final: LN(dyn,lnc1), LN(sta,lnc2), (dyn-sta)^2 @ Wcls, sigmoid, masked mean ----
  {
    float* red = (float*)pool;
    float pd[2][4], qd[2][4], psx[2][4], qsx[2][4];
#pragma unroll
    for (int m = 0; m < 2; ++m)
#pragma unroll
      for (int i = 0; i < 4; ++i) {
        float a = 0.f, b = 0.f, c = 0.f, d = 0.f;
#pragma unroll
        for (int n = 0; n < 4; ++n) {
          float v = dacc[m][n][i], w = sacc[m][n][i];
          a += v;
          b += v * v;
          c += w;
          d += w * w;
        }
#pragma unroll
        for (int o = 1; o < 16; o <<= 1) {
          a += __shfl_xor(a, o);
          b += __shfl_xor(b, o);
          c += __shfl_xor(c, o);
          d += __shfl_xor(d, o);
        }
        pd[m][i] = a;
        qd[m][i] = b;
        psx[m][i] = c;
        qsx[m][i] = d;
      }
    __syncthreads();  // prior red reads done everywhere before overwrite
    if (sr == 0)
#pragma unroll
      for (int m = 0; m < 2; ++m)
#pragma unroll
        for (int i = 0; i < 4; ++i) {
          int row = m * 16 + g * 4 + i;
          red[row * 4 + wid] = pd[m][i];
          red[128 + row * 4 + wid] = qd[m][i];
          red[256 + row * 4 + wid] = psx[m][i];
          red[384 + row * 4 + wid] = qsx[m][i];
        }
    __syncthreads();
    if (tid < 32) {
      float a = 0.f, b = 0.f, c = 0.f, d = 0.f;
#pragma unroll
      for (int w = 0; w < 4; ++w) {
        a += red[tid * 4 + w];
        b += red[128 + tid * 4 + w];
        c += red[256 + tid * 4 + w];
        d += red[384 + tid * 4 + w];
      }
      float muD = a * (1.f / 256.f), muS = c * (1.f / 256.f);
      s_a[tid] = muD;
      s_b[tid] = rsqrtf(b * (1.f / 256.f) - muD * muD + 1e-5f);
      s_c[tid] = muS;
      s_d[tid] = rsqrtf(d * (1.f / 256.f) - muS * muS + 1e-5f);
    }
    __syncthreads();
    float pp[2][4] = {};
#pragma unroll
    for (int m = 0; m < 2; ++m)
#pragma unroll
      for (int n = 0; n < 4; ++n)
#pragma unroll
        for (int i = 0; i < 4; ++i) {
          int row = m * 16 + g * 4 + i, col = wid * 64 + n * 16 + sr;
          float dn = (dacc[m][n][i] - s_a[row]) * s_b[row] * lnc1_g[col] + lnc1_b[col];
          float st = (sacc[m][n][i] - s_c[row]) * s_d[row] * lnc2_g[col] + lnc2_b[col];
          float df = dn - st;
          pp[m][i] = fmaf(df * df, Wcls[col], pp[m][i]);
        }
#pragma unroll
    for (int m = 0; m < 2; ++m)
#pragma unroll
      for (int i = 0; i < 4; ++i)
#pragma unroll
        for (int o = 1; o < 16; o <<= 1) pp[m][i] += __shfl_xor(pp[m][i], o);
    __syncthreads();
    if (sr == 0)
#pragma unroll
      for (int m = 0; m < 2; ++m)
#pragma unroll
        for (int i = 0; i < 4; ++i) red[(m * 16 + g * 4 + i) * 4 + wid] = pp[m][i];
    __syncthreads();
    if (tid < 32) {
      float s = red[tid * 4] + red[tid * 4 + 1] + red[tid * 4 + 2] + red[tid * 4 + 3] + bcls[0];
      s_prob[tid] = s_npm[tid] / (1.f + __expf(-s));
    }
    __syncthreads();
    if (tid < 2) {
      float psum = 0.f, nsum = 0.f;
#pragma unroll
      for (int r = 0; r < 16; ++r) {
        psum += s_prob[tid * 16 + r];
        nsum += s_npm[tid * 16 + r];
      }
      out[b0 + tid] = psum / nsum;
    }
  }
}

// ---- prep: fp32 weights -> bf16 (qkv pre-scaled by ln gammas) + (G,B) epilogue vectors ----
__global__ void prep_all(const float* __restrict__ Wq, const float* __restrict__ Wk,
                         const float* __restrict__ Wv, const float* __restrict__ Wfc1,
                         const float* __restrict__ p1w1, const float* __restrict__ p1w2,
                         const float* __restrict__ p2w1, const float* __restrict__ p2w2,
                         const float* __restrict__ g1, const float* __restrict__ b1,
                         const float* __restrict__ g2, const float* __restrict__ b2,
                         const float* __restrict__ g3, const float* __restrict__ b3,
                         u16* __restrict__ ws, float* __restrict__ aux) {
  int bx = blockIdx.x, t = threadIdx.x;
  if (bx >= 1536) {
    int m = bx - 1536;
    const float* W = (m == 0) ? Wq : (m == 1) ? Wk : Wv;
    const float* gg = (m == 0) ? g1 : (m == 1) ? g2 : g3;
    const float* bb = (m == 0) ? b1 : (m == 1) ? b2 : b3;
    float G = 0.f, Bv = 0.f;
    for (int k = 0; k < 128; ++k) {
      float w = W[t * 128 + k];
      G += w * gg[k];
      Bv += w * bb[k];
    }
    aux[m * 512 + t] = G;
    aux[m * 512 + 256 + t] = Bv;
    return;
  }
  const float* src;
  u16* dst;
  const float* sc = nullptr;
  int base;
  if (bx < 128) {
    src = Wq; dst = ws; sc = g1; base = bx;
  } else if (bx < 256) {
    src = Wk; dst = ws + 32768; sc = g2; base = bx - 128;
  } else if (bx < 384) {
    src = Wv; dst = ws + 65536; sc = g3; base = bx - 256;
  } else if (bx < 640) {
    src = Wfc1; dst = ws + 98304; base = bx - 384;
  } else if (bx < 896) {
    src = p1w1; dst = ws + 163840; base = bx - 640;
  } else if (bx < 1152) {
    src = p1w2; dst = ws + 229376; base = bx - 896;
  } else if (bx < 1280) {
    src = p2w1; dst = ws + 294912; base = bx - 1152;
  } else {
    src = p2w2; dst = ws + 327680; base = bx - 1280;
  }
  int i = base * 256 + t;
  float v = src[i];
  if (sc) v *= sc[i & 127];
  dst[i] = bfb(v);
}

extern "C" void kernel_launch(void* const* d_in, const int* in_sizes, int n_in,
                              void* d_out, int out_size, void* d_ws, size_t ws_size,
                              hipStream_t stream) {
  const int* x = (const int*)d_in[0];
  const float* node_emb = (const float*)d_in[1];
  const float* ln1_g = (const float*)d_in[2];
  const float* ln1_b = (const float*)d_in[3];
  const float* ln2_g = (const float*)d_in[4];
  const float* ln2_b = (const float*)d_in[5];
  const float* ln3_g = (const float*)d_in[6];
  const float* ln3_b = (const float*)d_in[7];
  const float* Wq = (const float*)d_in[8];
  const float* Wk = (const float*)d_in[9];
  const float* Wv = (const float*)d_in[10];
  const float* Wfc1 = (const float*)d_in[11];
  const float* p1_w1 = (const float*)d_in[12];
  const float* p1_b1 = (const float*)d_in[13];
  const float* p1_w2 = (const float*)d_in[14];
  const float* p1_b2 = (const float*)d_in[15];
  const float* p1_lng = (const float*)d_in[16];
  const float* p1_lnb = (const float*)d_in[17];
  const float* p2_w1 = (const float*)d_in[18];
  const float* p2_b1 = (const float*)d_in[19];
  const float* p2_w2 = (const float*)d_in[20];
  const float* p2_b2 = (const float*)d_in[21];
  const float* lnc1_g = (const float*)d_in[22];
  const float* lnc1_b = (const float*)d_in[23];
  const float* lnc2_g = (const float*)d_in[24];
  const float* lnc2_b = (const float*)d_in[25];
  const float* Wcls = (const float*)d_in[26];
  const float* bcls = (const float*)d_in[27];

  u16* ws = (u16*)d_ws;
  float* aux = (float*)(ws + 393216);

  prep_all<<<1539, 256, 0, stream>>>(Wq, Wk, Wv, Wfc1, p1_w1, p1_w2, p2_w1, p2_w2, ln1_g, ln1_b,
                                     ln2_g, ln2_b, ln3_g, ln3_b, ws, aux);

  const int B = in_sizes[0] / 16;
  fused_kernel<<<B / 2, 256, 0, stream>>>(
      x, node_emb, ws, ws + 32768, ws + 65536, ws + 98304, ws + 163840, ws + 229376, ws + 294912,
      ws + 327680, aux, p1_b1, p1_b2, p1_lng, p1_lnb, p2_b1, p2_b2, lnc1_g, lnc1_b, lnc2_g, lnc2_b,
      Wcls, bcls, (float*)d_out);
}

// Round 3
// 470.954 us; speedup vs baseline: 6.8708x; 1.6410x over previous
//
#include <hip/hip_runtime.h>
#include <math.h>

typedef unsigned short u16;
typedef __bf16 bf16x8 __attribute__((ext_vector_type(8)));
typedef u16 u16x8 __attribute__((ext_vector_type(8)));
typedef float f32x4 __attribute__((ext_vector_type(4)));

// ---- LDS pool (u16 units), 25344 u16 = 49.5 KB -> 3 blocks/CU ----
// E  [32][136]: emb bf16 (alive whole kernel)
// B1 [32][264]: Q -> V_s (subtiled) -> DIN -> ST1
// B2 [32][264]: K -> CTX -> H1
// SC [16][16][16]: attn bf16; later f32 reduction scratch
#define E_O 0
#define E_S 136
#define B1_O 4352
#define B2_O 12800
#define ACT_S 264
#define SC_O 21248
#define POOL_U 25344

__device__ __forceinline__ u16 bfb(float f) {
  unsigned u = __builtin_bit_cast(unsigned, f);
  unsigned r = u + 0x7fffu + ((u >> 16) & 1u);
  return (u16)(r >> 16);
}
__device__ __forceinline__ float tanh_f(float x) {
  float e = __expf(2.f * x);
  return 1.f - 2.f / (e + 1.f);
}

// out[l][n] += sum_k act[l][k] * W[n][k]
template <int K, int SS>
__device__ __forceinline__ void mm_acc(const u16* sA, const u16* __restrict__ W,
                                       f32x4 acc[2][4], int wid, int g, int sr) {
  const int ko = g * 8;
#pragma unroll
  for (int k0 = 0; k0 < K; k0 += 32) {
    bf16x8 a0 = *(const bf16x8*)(sA + sr * SS + k0 + ko);
    bf16x8 a1 = *(const bf16x8*)(sA + (16 + sr) * SS + k0 + ko);
#pragma unroll
    for (int n = 0; n < 4; ++n) {
      bf16x8 bw = *(const bf16x8*)(W + (size_t)(wid * 64 + n * 16 + sr) * K + k0 + ko);
      acc[0][n] = __builtin_amdgcn_mfma_f32_16x16x32_bf16(a0, bw, acc[0][n], 0, 0, 0);
      acc[1][n] = __builtin_amdgcn_mfma_f32_16x16x32_bf16(a1, bw, acc[1][n], 0, 0, 0);
    }
  }
}

__global__ __launch_bounds__(256, 3) void fused_kernel(
    const int* __restrict__ x, const float* __restrict__ node_emb,
    const u16* __restrict__ wq, const u16* __restrict__ wk, const u16* __restrict__ wv,
    const u16* __restrict__ wfc1, const u16* __restrict__ w11, const u16* __restrict__ w12,
    const u16* __restrict__ w21, const u16* __restrict__ w22,
    const float* __restrict__ aux,
    const float* __restrict__ p1_b1, const float* __restrict__ p1_b2,
    const float* __restrict__ p1_lng, const float* __restrict__ p1_lnb,
    const float* __restrict__ p2_b1, const float* __restrict__ p2_b2,
    const float* __restrict__ lnc1_g, const float* __restrict__ lnc1_b,
    const float* __restrict__ lnc2_g, const float* __restrict__ lnc2_b,
    const float* __restrict__ Wcls, const float* __restrict__ bcls,
    float* __restrict__ out) {
  __shared__ __align__(16) u16 pool[POOL_U];
  __shared__ int s_xi[32];
  __shared__ float s_npm[32], s_mu[32], s_rs[32];
  __shared__ float s_a[32], s_b[32], s_c[32], s_d[32];
  __shared__ float s_prob[32];

  const int tid = threadIdx.x;
  const int wid = tid >> 6, lane = tid & 63;
  const int g = lane >> 4, sr = lane & 15;
  const int b0 = blockIdx.x * 2;

  if (tid < 32) {
    int xi = x[b0 * 16 + tid];
    s_xi[tid] = xi;
    s_npm[tid] = (xi != 0) ? 1.f : 0.f;
  }
  __syncthreads();

  // ---- gather emb (fp32 -> bf16 LDS) + LN stats (from fp32) ----
  {
    const int row = tid >> 3, j = tid & 7;
    const float4* src = (const float4*)(node_emb + (size_t)s_xi[row] * 128 + j * 16);
    u16* dst = pool + E_O + row * E_S + j * 16;
    float su = 0.f, sq = 0.f;
#pragma unroll
    for (int q4 = 0; q4 < 4; ++q4) {
      float4 v = src[q4];
      su += v.x + v.y + v.z + v.w;
      sq += v.x * v.x + v.y * v.y + v.z * v.z + v.w * v.w;
      dst[q4 * 4 + 0] = bfb(v.x);
      dst[q4 * 4 + 1] = bfb(v.y);
      dst[q4 * 4 + 2] = bfb(v.z);
      dst[q4 * 4 + 3] = bfb(v.w);
    }
#pragma unroll
    for (int o = 1; o < 8; o <<= 1) {
      su += __shfl_xor(su, o);
      sq += __shfl_xor(sq, o);
    }
    if (j == 0) {
      float mu = su * (1.f / 128.f);
      s_mu[row] = mu;
      s_rs[row] = rsqrtf(sq * (1.f / 128.f) - mu * mu + 1e-5f);
    }
  }
  __syncthreads();

  // ---- Q -> B1, K -> B2 (LN folded: pre-scaled weights + G/B epilogue), V -> regs ----
  f32x4 vacc[2][4] = {};
  {
#pragma unroll
    for (int p = 0; p < 3; ++p) {
      const u16* W = (p == 0) ? wq : (p == 1) ? wk : wv;
      const float* G = aux + p * 512;
      const float* Bv = aux + p * 512 + 256;
      f32x4 acc[2][4] = {};
      mm_acc<128, E_S>(pool + E_O, W, acc, wid, g, sr);
#pragma unroll
      for (int m = 0; m < 2; ++m)
#pragma unroll
        for (int n = 0; n < 4; ++n)
#pragma unroll
          for (int i = 0; i < 4; ++i) {
            int row = m * 16 + g * 4 + i, col = wid * 64 + n * 16 + sr;
            float v = s_rs[row] * (acc[m][n][i] - s_mu[row] * G[col]) + Bv[col];
            if (p == 2)
              vacc[m][n][i] = v;
            else
              pool[((p == 0) ? B1_O : B2_O) + row * ACT_S + col] = bfb(v);
          }
    }
  }
  __syncthreads();

  // ---- scores (MFMA K=32) + diag mask + softmax -> SC bf16 [pair][l][m] ----
  {
#pragma unroll
    for (int pi = 0; pi < 4; ++pi) {
      int pair = wid * 4 + pi, pb = pair >> 3, h = pair & 7;
      bf16x8 qa = *(const bf16x8*)(pool + B1_O + (pb * 16 + sr) * ACT_S + h * 32 + g * 8);
      bf16x8 kb = *(const bf16x8*)(pool + B2_O + (pb * 16 + sr) * ACT_S + h * 32 + g * 8);
      f32x4 z = {};
      f32x4 sc = __builtin_amdgcn_mfma_f32_16x16x32_bf16(qa, kb, z, 0, 0, 0);
#pragma unroll
      for (int i = 0; i < 4; ++i) {
        int l = g * 4 + i;
        float v = sc[i] * 0.17677669529663687f;
        if (sr == l) v = -3.0e38f;
        float mx = v;
#pragma unroll
        for (int o = 1; o < 16; o <<= 1) mx = fmaxf(mx, __shfl_xor(mx, o));
        float e = (sr == l) ? 0.f : __expf(v - mx);
        float s = e;
#pragma unroll
        for (int o = 1; o < 16; o <<= 1) s += __shfl_xor(s, o);
        pool[SC_O + pair * 256 + l * 16 + sr] = bfb(e / s);
      }
    }
  }
  __syncthreads();  // SC visible; B1(Q) reads done

  // ---- V_s: subtiled [elem][k/8][col][8] into B1 (Q dead) ----
  {
#pragma unroll
    for (int m = 0; m < 2; ++m)
#pragma unroll
      for (int n = 0; n < 4; ++n)
#pragma unroll
        for (int i = 0; i < 4; ++i) {
          int k = g * 4 + i, col = wid * 64 + n * 16 + sr;
          pool[B1_O + m * 4112 + (k >> 3) * 2056 + col * 8 + (k & 7)] = bfb(vacc[m][n][i]);
        }
  }
  __syncthreads();

  // ---- PV: ctx = attn @ V (b128 B-reads) -> B2 (K dead) ----
  {
#pragma unroll
    for (int pi = 0; pi < 4; ++pi) {
      int pair = wid * 4 + pi, pb = pair >> 3, h = pair & 7;
      u16x8 ta = {};
      if (g < 2) ta = *(const u16x8*)(pool + SC_O + pair * 256 + sr * 16 + g * 8);
      bf16x8 pa = __builtin_bit_cast(bf16x8, ta);
#pragma unroll
      for (int dt = 0; dt < 2; ++dt) {
        int dcol = h * 32 + dt * 16 + sr;
        bf16x8 vb = *(const bf16x8*)(pool + B1_O + pb * 4112 + (g & 1) * 2056 + dcol * 8);
        f32x4 z = {};
        f32x4 c = __builtin_amdgcn_mfma_f32_16x16x32_bf16(pa, vb, z, 0, 0, 0);
#pragma unroll
        for (int i = 0; i < 4; ++i)
          pool[B2_O + (pb * 16 + g * 4 + i) * ACT_S + dcol] = bfb(c[i]);
      }
    }
  }
  __syncthreads();  // CTX visible; SC + V_s reads done

  // ---- P6: dyn_in = (ctx @ Wfc1^T)*npm -> rin regs + DIN bf16 -> B1 ----
  f32x4 rin[2][4] = {};
  mm_acc<256, ACT_S>(pool + B2_O, wfc1, rin, wid, g, sr);
#pragma unroll
  for (int m = 0; m < 2; ++m)
#pragma unroll
    for (int n = 0; n < 4; ++n)
#pragma unroll
      for (int i = 0; i < 4; ++i) {
        int row = m * 16 + g * 4 + i, col = wid * 64 + n * 16 + sr;
        rin[m][n][i] *= s_npm[row];
        pool[B1_O + row * ACT_S + col] = bfb(rin[m][n][i]);
      }
  __syncthreads();

  // ---- P7: h1 = tanh(din @ p1w1^T + b1) -> B2 (ctx dead) ----
  {
    f32x4 acc[2][4] = {};
    mm_acc<256, ACT_S>(pool + B1_O, w11, acc, wid, g, sr);
    const float bias = p1_b1[wid * 64 + sr];  // col depends on n too; load per-n below
#pragma unroll
    for (int m = 0; m < 2; ++m)
#pragma unroll
      for (int n = 0; n < 4; ++n)
#pragma unroll
        for (int i = 0; i < 4; ++i) {
          int row = m * 16 + g * 4 + i, col = wid * 64 + n * 16 + sr;
          float bn = (n == 0) ? bias : p1_b1[col];
          pool[B2_O + row * ACT_S + col] = bfb(tanh_f(acc[m][n][i] + bn));
        }
  }
  __syncthreads();

  // ---- P8: dacc = h1@p1w2^T + b2 + rin; row-LN(p1_ln)*npm -> dacc regs ----
  f32x4 dacc[2][4] = {};
  mm_acc<256, ACT_S>(pool + B2_O, w12, dacc, wid, g, sr);
#pragma unroll
  for (int m = 0; m < 2; ++m)
#pragma unroll
    for (int n = 0; n < 4; ++n)
#pragma unroll
      for (int i = 0; i < 4; ++i) {
        int col = wid * 64 + n * 16 + sr;
        dacc[m][n][i] += p1_b2[col] + rin[m][n][i];
      }
  {
    float* red = (float*)(pool + SC_O);
    float ps[2][4], pq[2][4];
#pragma unroll
    for (int m = 0; m < 2; ++m)
#pragma unroll
      for (int i = 0; i < 4; ++i) {
        float a = 0.f, b = 0.f;
#pragma unroll
        for (int n = 0; n < 4; ++n) {
          float v = dacc[m][n][i];
          a += v;
          b += v * v;
        }
#pragma unroll
        for (int o = 1; o < 16; o <<= 1) {
          a += __shfl_xor(a, o);
          b += __shfl_xor(b, o);
        }
        ps[m][i] = a;
        pq[m][i] = b;
      }
    if (sr == 0)
#pragma unroll
      for (int m = 0; m < 2; ++m)
#pragma unroll
        for (int i = 0; i < 4; ++i) {
          int row = m * 16 + g * 4 + i;
          red[row * 4 + wid] = ps[m][i];
          red[128 + row * 4 + wid] = pq[m][i];
        }
    __syncthreads();
    if (tid < 32) {
      float a = 0.f, b = 0.f;
#pragma unroll
      for (int w = 0; w < 4; ++w) {
        a += red[tid * 4 + w];
        b += red[128 + tid * 4 + w];
      }
      float mu = a * (1.f / 256.f);
      s_a[tid] = mu;
      s_b[tid] = rsqrtf(b * (1.f / 256.f) - mu * mu + 1e-5f);
    }
    __syncthreads();
#pragma unroll
    for (int m = 0; m < 2; ++m)
#pragma unroll
      for (int n = 0; n < 4; ++n)
#pragma unroll
        for (int i = 0; i < 4; ++i) {
          int row = m * 16 + g * 4 + i, col = wid * 64 + n * 16 + sr;
          dacc[m][n][i] =
              ((dacc[m][n][i] - s_a[row]) * s_b[row] * p1_lng[col] + p1_lnb[col]) * s_npm[row];
        }
  }

  // ---- P9: st1 = tanh(npm*(emb @ p2w1^T) + b1) -> B1 (din dead) ----
  {
    f32x4 acc[2][4] = {};
    mm_acc<128, E_S>(pool + E_O, w21, acc, wid, g, sr);
#pragma unroll
    for (int m = 0; m < 2; ++m)
#pragma unroll
      for (int n = 0; n < 4; ++n)
#pragma unroll
        for (int i = 0; i < 4; ++i) {
          int row = m * 16 + g * 4 + i, col = wid * 64 + n * 16 + sr;
          pool[B1_O + row * ACT_S + col] = bfb(tanh_f(s_npm[row] * acc[m][n][i] + p2_b1[col]));
        }
  }
  __syncthreads();

  // ---- P10: static = (st1 @ p2w2^T + b2)*npm -> sacc regs ----
  f32x4 sacc[2][4] = {};
  mm_acc<256, ACT_S>(pool + B1_O, w22, sacc, wid, g, sr);
#pragma unroll
  for (int m = 0; m < 2; ++m)
#pragma unroll
    for (int n = 0; n < 4; ++n)
#pragma unroll
      for (int i = 0; i < 4; ++i) {
        int row = m * 16 + g * 4 + i, col = wid * 64 + n * 16 + sr;
        sacc[m][n][i] = (sacc[m][n][i] + p2_b2[col]) * s_npm[row];
      }

  // ---- final: LN(dyn,lnc1), LN(sta,lnc2), (dyn-sta)^2 @ Wcls, sigmoid, masked mean ----
  {
    float* red = (float*)(pool + SC_O);
    float pd[2][4], qd[2][4], psx[2][4], qsx[2][4];
#pragma unroll
    for (int m = 0; m < 2; ++m)
#pragma unroll
      for (int i = 0; i < 4; ++i) {
        float a = 0.f, b = 0.f, c = 0.f, d = 0.f;
#pragma unroll
        for (int n = 0; n < 4; ++n) {
          float v = dacc[m][n][i], w = sacc[m][n][i];
          a += v;
          b += v * v;
          c += w;
          d += w * w;
        }
#pragma unroll
        for (int o = 1; o < 16; o <<= 1) {
          a += __shfl_xor(a, o);
          b += __shfl_xor(b, o);
          c += __shfl_xor(c, o);
          d += __shfl_xor(d, o);
        }
        pd[m][i] = a;
        qd[m][i] = b;
        psx[m][i] = c;
        qsx[m][i] = d;
      }
    __syncthreads();  // P8's red reads done on all waves before overwrite
    if (sr == 0)
#pragma unroll
      for (int m = 0; m < 2; ++m)
#pragma unroll
        for (int i = 0; i < 4; ++i) {
          int row = m * 16 + g * 4 + i;
          red[row * 4 + wid] = pd[m][i];
          red[128 + row * 4 + wid] = qd[m][i];
          red[256 + row * 4 + wid] = psx[m][i];
          red[384 + row * 4 + wid] = qsx[m][i];
        }
    __syncthreads();
    if (tid < 32) {
      float a = 0.f, b = 0.f, c = 0.f, d = 0.f;
#pragma unroll
      for (int w = 0; w < 4; ++w) {
        a += red[tid * 4 + w];
        b += red[128 + tid * 4 + w];
        c += red[256 + tid * 4 + w];
        d += red[384 + tid * 4 + w];
      }
      float muD = a * (1.f / 256.f), muS = c * (1.f / 256.f);
      s_a[tid] = muD;
      s_b[tid] = rsqrtf(b * (1.f / 256.f) - muD * muD + 1e-5f);
      s_c[tid] = muS;
      s_d[tid] = rsqrtf(d * (1.f / 256.f) - muS * muS + 1e-5f);
    }
    __syncthreads();
    float pp[2][4] = {};
#pragma unroll
    for (int m = 0; m < 2; ++m)
#pragma unroll
      for (int n = 0; n < 4; ++n)
#pragma unroll
        for (int i = 0; i < 4; ++i) {
          int row = m * 16 + g * 4 + i, col = wid * 64 + n * 16 + sr;
          float dn = (dacc[m][n][i] - s_a[row]) * s_b[row] * lnc1_g[col] + lnc1_b[col];
          float st = (sacc[m][n][i] - s_c[row]) * s_d[row] * lnc2_g[col] + lnc2_b[col];
          float df = dn - st;
          pp[m][i] = fmaf(df * df, Wcls[col], pp[m][i]);
        }
#pragma unroll
    for (int m = 0; m < 2; ++m)
#pragma unroll
      for (int i = 0; i < 4; ++i)
#pragma unroll
        for (int o = 1; o < 16; o <<= 1) pp[m][i] += __shfl_xor(pp[m][i], o);
    __syncthreads();
    if (sr == 0)
#pragma unroll
      for (int m = 0; m < 2; ++m)
#pragma unroll
        for (int i = 0; i < 4; ++i) red[(m * 16 + g * 4 + i) * 4 + wid] = pp[m][i];
    __syncthreads();
    if (tid < 32) {
      float s = red[tid * 4] + red[tid * 4 + 1] + red[tid * 4 + 2] + red[tid * 4 + 3] + bcls[0];
      s_prob[tid] = s_npm[tid] / (1.f + __expf(-s));
    }
    __syncthreads();
    if (tid < 2) {
      float psum = 0.f, nsum = 0.f;
#pragma unroll
      for (int r = 0; r < 16; ++r) {
        psum += s_prob[tid * 16 + r];
        nsum += s_npm[tid * 16 + r];
      }
      out[b0 + tid] = psum / nsum;
    }
  }
}

// ---- prep: fp32 weights -> bf16 (qkv pre-scaled by ln gammas) + (G,B) epilogue vectors ----
__global__ void prep_all(const float* __restrict__ Wq, const float* __restrict__ Wk,
                         const float* __restrict__ Wv, const float* __restrict__ Wfc1,
                         const float* __restrict__ p1w1, const float* __restrict__ p1w2,
                         const float* __restrict__ p2w1, const float* __restrict__ p2w2,
                         const float* __restrict__ g1, const float* __restrict__ b1,
                         const float* __restrict__ g2, const float* __restrict__ b2,
                         const float* __restrict__ g3, const float* __restrict__ b3,
                         u16* __restrict__ ws, float* __restrict__ aux) {
  int bx = blockIdx.x, t = threadIdx.x;
  if (bx >= 1536) {
    int m = bx - 1536;
    const float* W = (m == 0) ? Wq : (m == 1) ? Wk : Wv;
    const float* gg = (m == 0) ? g1 : (m == 1) ? g2 : g3;
    const float* bb = (m == 0) ? b1 : (m == 1) ? b2 : b3;
    float G = 0.f, Bv = 0.f;
    for (int k = 0; k < 128; ++k) {
      float w = W[t * 128 + k];
      G += w * gg[k];
      Bv += w * bb[k];
    }
    aux[m * 512 + t] = G;
    aux[m * 512 + 256 + t] = Bv;
    return;
  }
  const float* src;
  u16* dst;
  const float* sc = nullptr;
  int base;
  if (bx < 128) {
    src = Wq; dst = ws; sc = g1; base = bx;
  } else if (bx < 256) {
    src = Wk; dst = ws + 32768; sc = g2; base = bx - 128;
  } else if (bx < 384) {
    src = Wv; dst = ws + 65536; sc = g3; base = bx - 256;
  } else if (bx < 640) {
    src = Wfc1; dst = ws + 98304; base = bx - 384;
  } else if (bx < 896) {
    src = p1w1; dst = ws + 163840; base = bx - 640;
  } else if (bx < 1152) {
    src = p1w2; dst = ws + 229376; base = bx - 896;
  } else if (bx < 1280) {
    src = p2w1; dst = ws + 294912; base = bx - 1152;
  } else {
    src = p2w2; dst = ws + 327680; base = bx - 1280;
  }
  int i = base * 256 + t;
  float v = src[i];
  if (sc) v *= sc[i & 127];
  dst[i] = bfb(v);
}

extern "C" void kernel_launch(void* const* d_in, const int* in_sizes, int n_in,
                              void* d_out, int out_size, void* d_ws, size_t ws_size,
                              hipStream_t stream) {
  const int* x = (const int*)d_in[0];
  const float* node_emb = (const float*)d_in[1];
  const float* ln1_g = (const float*)d_in[2];
  const float* ln1_b = (const float*)d_in[3];
  const float* ln2_g = (const float*)d_in[4];
  const float* ln2_b = (const float*)d_in[5];
  const float* ln3_g = (const float*)d_in[6];
  const float* ln3_b = (const float*)d_in[7];
  const float* Wq = (const float*)d_in[8];
  const float* Wk = (const float*)d_in[9];
  const float* Wv = (const float*)d_in[10];
  const float* Wfc1 = (const float*)d_in[11];
  const float* p1_w1 = (const float*)d_in[12];
  const float* p1_b1 = (const float*)d_in[13];
  const float* p1_w2 = (const float*)d_in[14];
  const float* p1_b2 = (const float*)d_in[15];
  const float* p1_lng = (const float*)d_in[16];
  const float* p1_lnb = (const float*)d_in[17];
  const float* p2_w1 = (const float*)d_in[18];
  const float* p2_b1 = (const float*)d_in[19];
  const float* p2_w2 = (const float*)d_in[20];
  const float* p2_b2 = (const float*)d_in[21];
  const float* lnc1_g = (const float*)d_in[22];
  const float* lnc1_b = (const float*)d_in[23];
  const float* lnc2_g = (const float*)d_in[24];
  const float* lnc2_b = (const float*)d_in[25];
  const float* Wcls = (const float*)d_in[26];
  const float* bcls = (const float*)d_in[27];

  u16* ws = (u16*)d_ws;
  float* aux = (float*)(ws + 393216);

  prep_all<<<1539, 256, 0, stream>>>(Wq, Wk, Wv, Wfc1, p1_w1, p1_w2, p2_w1, p2_w2, ln1_g, ln1_b,
                                     ln2_g, ln2_b, ln3_g, ln3_b, ws, aux);

  const int B = in_sizes[0] / 16;
  fused_kernel<<<B / 2, 256, 0, stream>>>(
      x, node_emb, ws, ws + 32768, ws + 65536, ws + 98304, ws + 163840, ws + 229376, ws + 294912,
      ws + 327680, aux, p1_b1, p1_b2, p1_lng, p1_lnb, p2_b1, p2_b2, lnc1_g, lnc1_b, lnc2_g, lnc2_b,
      Wcls, bcls, (float*)d_out);
}

// Round 4
// 434.657 us; speedup vs baseline: 7.4445x; 1.0835x over previous
//
#include <hip/hip_runtime.h>
#include <math.h>

typedef unsigned short u16;
typedef __bf16 bf16x8 __attribute__((ext_vector_type(8)));
typedef u16 u16x8 __attribute__((ext_vector_type(8)));
typedef float f32x4 __attribute__((ext_vector_type(4)));

// ---- LDS pool (u16 units), 25344 u16 = 49.5 KB -> 3 blocks/CU ----
// E  [32][136]: emb bf16 (alive whole kernel)
// B1 [32][264]: Q -> V_s (subtiled) -> DIN -> ST1
// B2 [32][264]: K -> CTX -> H1
// SC [16][16][16]: attn bf16; later f32 reduction scratch
#define E_O 0
#define E_S 136
#define B1_O 4352
#define B2_O 12800
#define ACT_S 264
#define SC_O 21248
#define POOL_U 25344

__device__ __forceinline__ u16 bfb(float f) {
  unsigned u = __builtin_bit_cast(unsigned, f);
  unsigned r = u + 0x7fffu + ((u >> 16) & 1u);
  return (u16)(r >> 16);
}
__device__ __forceinline__ float tanh_f(float x) {
  float e = __expf(2.f * x);
  return 1.f - 2.f / (e + 1.f);
}

// out[l][n] += sum_k act[l][k] * W[n][k]
template <int K, int SS>
__device__ __forceinline__ void mm_acc(const u16* sA, const u16* __restrict__ W,
                                       f32x4 acc[2][4], int wid, int g, int sr) {
  const int ko = g * 8;
#pragma unroll
  for (int k0 = 0; k0 < K; k0 += 32) {
    bf16x8 a0 = *(const bf16x8*)(sA + sr * SS + k0 + ko);
    bf16x8 a1 = *(const bf16x8*)(sA + (16 + sr) * SS + k0 + ko);
#pragma unroll
    for (int n = 0; n < 4; ++n) {
      bf16x8 bw = *(const bf16x8*)(W + (size_t)(wid * 64 + n * 16 + sr) * K + k0 + ko);
      acc[0][n] = __builtin_amdgcn_mfma_f32_16x16x32_bf16(a0, bw, acc[0][n], 0, 0, 0);
      acc[1][n] = __builtin_amdgcn_mfma_f32_16x16x32_bf16(a1, bw, acc[1][n], 0, 0, 0);
    }
  }
}

__global__ __launch_bounds__(256) void fused_kernel(
    const int* __restrict__ x, const float* __restrict__ node_emb,
    const u16* __restrict__ wq, const u16* __restrict__ wk, const u16* __restrict__ wv,
    const u16* __restrict__ wfc1, const u16* __restrict__ w11, const u16* __restrict__ w12,
    const u16* __restrict__ w21, const u16* __restrict__ w22,
    const float* __restrict__ aux,
    const float* __restrict__ p1_b1, const float* __restrict__ p1_b2,
    const float* __restrict__ p1_lng, const float* __restrict__ p1_lnb,
    const float* __restrict__ p2_b1, const float* __restrict__ p2_b2,
    const float* __restrict__ lnc1_g, const float* __restrict__ lnc1_b,
    const float* __restrict__ lnc2_g, const float* __restrict__ lnc2_b,
    const float* __restrict__ Wcls, const float* __restrict__ bcls,
    float* __restrict__ out) {
  __shared__ __align__(16) u16 pool[POOL_U];
  __shared__ int s_xi[32];
  __shared__ float s_npm[32], s_mu[32], s_rs[32];
  __shared__ float s_a[32], s_b[32], s_c[32], s_d[32];
  __shared__ float s_prob[32];

  const int tid = threadIdx.x;
  const int wid = tid >> 6, lane = tid & 63;
  const int g = lane >> 4, sr = lane & 15;
  const int b0 = blockIdx.x * 2;

  if (tid < 32) {
    int xi = x[b0 * 16 + tid];
    s_xi[tid] = xi;
    s_npm[tid] = (xi != 0) ? 1.f : 0.f;
  }
  __syncthreads();

  // ---- gather emb (fp32 -> bf16 LDS) + LN stats (from fp32) ----
  {
    const int row = tid >> 3, j = tid & 7;
    const float4* src = (const float4*)(node_emb + (size_t)s_xi[row] * 128 + j * 16);
    u16* dst = pool + E_O + row * E_S + j * 16;
    float su = 0.f, sq = 0.f;
#pragma unroll
    for (int q4 = 0; q4 < 4; ++q4) {
      float4 v = src[q4];
      su += v.x + v.y + v.z + v.w;
      sq += v.x * v.x + v.y * v.y + v.z * v.z + v.w * v.w;
      dst[q4 * 4 + 0] = bfb(v.x);
      dst[q4 * 4 + 1] = bfb(v.y);
      dst[q4 * 4 + 2] = bfb(v.z);
      dst[q4 * 4 + 3] = bfb(v.w);
    }
#pragma unroll
    for (int o = 1; o < 8; o <<= 1) {
      su += __shfl_xor(su, o);
      sq += __shfl_xor(sq, o);
    }
    if (j == 0) {
      float mu = su * (1.f / 128.f);
      s_mu[row] = mu;
      s_rs[row] = rsqrtf(sq * (1.f / 128.f) - mu * mu + 1e-5f);
    }
  }
  __syncthreads();

  // ---- Q -> B1, K -> B2 (LN folded: pre-scaled weights + G/B epilogue) ----
  {
#pragma unroll
    for (int p = 0; p < 2; ++p) {
      const u16* W = (p == 0) ? wq : wk;
      const float* G = aux + p * 512;
      const float* Bv = aux + p * 512 + 256;
      f32x4 acc[2][4] = {};
      mm_acc<128, E_S>(pool + E_O, W, acc, wid, g, sr);
#pragma unroll
      for (int m = 0; m < 2; ++m)
#pragma unroll
        for (int n = 0; n < 4; ++n)
#pragma unroll
          for (int i = 0; i < 4; ++i) {
            int row = m * 16 + g * 4 + i, col = wid * 64 + n * 16 + sr;
            float v = s_rs[row] * (acc[m][n][i] - s_mu[row] * G[col]) + Bv[col];
            pool[((p == 0) ? B1_O : B2_O) + row * ACT_S + col] = bfb(v);
          }
    }
  }
  __syncthreads();

  // ---- scores (MFMA K=32) + diag mask + softmax -> SC bf16 [pair][l][m] ----
  {
#pragma unroll
    for (int pi = 0; pi < 4; ++pi) {
      int pair = wid * 4 + pi, pb = pair >> 3, h = pair & 7;
      bf16x8 qa = *(const bf16x8*)(pool + B1_O + (pb * 16 + sr) * ACT_S + h * 32 + g * 8);
      bf16x8 kb = *(const bf16x8*)(pool + B2_O + (pb * 16 + sr) * ACT_S + h * 32 + g * 8);
      f32x4 z = {};
      f32x4 sc = __builtin_amdgcn_mfma_f32_16x16x32_bf16(qa, kb, z, 0, 0, 0);
#pragma unroll
      for (int i = 0; i < 4; ++i) {
        int l = g * 4 + i;
        float v = sc[i] * 0.17677669529663687f;
        if (sr == l) v = -3.0e38f;
        float mx = v;
#pragma unroll
        for (int o = 1; o < 16; o <<= 1) mx = fmaxf(mx, __shfl_xor(mx, o));
        float e = (sr == l) ? 0.f : __expf(v - mx);
        float s = e;
#pragma unroll
        for (int o = 1; o < 16; o <<= 1) s += __shfl_xor(s, o);
        pool[SC_O + pair * 256 + l * 16 + sr] = bfb(e / s);
      }
    }
  }
  __syncthreads();  // SC visible; B1(Q)/B2(K) reads done

  // ---- V = LN3(emb) @ wv^T -> B1 subtiled [elem][k/8][col][8] (Q dead) ----
  {
    const float* G = aux + 2 * 512;
    const float* Bv = aux + 2 * 512 + 256;
    f32x4 acc[2][4] = {};
    mm_acc<128, E_S>(pool + E_O, wv, acc, wid, g, sr);
#pragma unroll
    for (int m = 0; m < 2; ++m)
#pragma unroll
      for (int n = 0; n < 4; ++n)
#pragma unroll
        for (int i = 0; i < 4; ++i) {
          int k = g * 4 + i, row = m * 16 + k, col = wid * 64 + n * 16 + sr;
          float v = s_rs[row] * (acc[m][n][i] - s_mu[row] * G[col]) + Bv[col];
          pool[B1_O + m * 4112 + (k >> 3) * 2056 + col * 8 + (k & 7)] = bfb(v);
        }
  }
  __syncthreads();

  // ---- PV: ctx = attn @ V (b128 B-reads) -> B2 (K dead) ----
  {
#pragma unroll
    for (int pi = 0; pi < 4; ++pi) {
      int pair = wid * 4 + pi, pb = pair >> 3, h = pair & 7;
      u16x8 ta = {};
      if (g < 2) ta = *(const u16x8*)(pool + SC_O + pair * 256 + sr * 16 + g * 8);
      bf16x8 pa = __builtin_bit_cast(bf16x8, ta);
#pragma unroll
      for (int dt = 0; dt < 2; ++dt) {
        int dcol = h * 32 + dt * 16 + sr;
        bf16x8 vb = *(const bf16x8*)(pool + B1_O + pb * 4112 + (g & 1) * 2056 + dcol * 8);
        f32x4 z = {};
        f32x4 c = __builtin_amdgcn_mfma_f32_16x16x32_bf16(pa, vb, z, 0, 0, 0);
#pragma unroll
        for (int i = 0; i < 4; ++i)
          pool[B2_O + (pb * 16 + g * 4 + i) * ACT_S + dcol] = bfb(c[i]);
      }
    }
  }
  __syncthreads();  // CTX visible; SC + V_s reads done

  // ---- P6: dyn_in = (ctx @ Wfc1^T)*npm -> rin regs + DIN bf16 -> B1 ----
  f32x4 rin[2][4] = {};
  mm_acc<256, ACT_S>(pool + B2_O, wfc1, rin, wid, g, sr);
#pragma unroll
  for (int m = 0; m < 2; ++m)
#pragma unroll
    for (int n = 0; n < 4; ++n)
#pragma unroll
      for (int i = 0; i < 4; ++i) {
        int row = m * 16 + g * 4 + i, col = wid * 64 + n * 16 + sr;
        rin[m][n][i] *= s_npm[row];
        pool[B1_O + row * ACT_S + col] = bfb(rin[m][n][i]);
      }
  __syncthreads();

  // ---- P7: h1 = tanh(din @ p1w1^T + b1) -> B2 (ctx dead) ----
  {
    f32x4 acc[2][4] = {};
    mm_acc<256, ACT_S>(pool + B1_O, w11, acc, wid, g, sr);
#pragma unroll
    for (int m = 0; m < 2; ++m)
#pragma unroll
      for (int n = 0; n < 4; ++n)
#pragma unroll
        for (int i = 0; i < 4; ++i) {
          int row = m * 16 + g * 4 + i, col = wid * 64 + n * 16 + sr;
          pool[B2_O + row * ACT_S + col] = bfb(tanh_f(acc[m][n][i] + p1_b1[col]));
        }
  }
  __syncthreads();

  // ---- P8: dacc = h1@p1w2^T + b2 + rin; row-LN(p1_ln)*npm -> dacc regs ----
  f32x4 dacc[2][4] = {};
  mm_acc<256, ACT_S>(pool + B2_O, w12, dacc, wid, g, sr);
#pragma unroll
  for (int m = 0; m < 2; ++m)
#pragma unroll
    for (int n = 0; n < 4; ++n)
#pragma unroll
      for (int i = 0; i < 4; ++i) {
        int col = wid * 64 + n * 16 + sr;
        dacc[m][n][i] += p1_b2[col] + rin[m][n][i];
      }
  {
    float* red = (float*)(pool + SC_O);
    float ps[2][4], pq[2][4];
#pragma unroll
    for (int m = 0; m < 2; ++m)
#pragma unroll
      for (int i = 0; i < 4; ++i) {
        float a = 0.f, b = 0.f;
#pragma unroll
        for (int n = 0; n < 4; ++n) {
          float v = dacc[m][n][i];
          a += v;
          b += v * v;
        }
#pragma unroll
        for (int o = 1; o < 16; o <<= 1) {
          a += __shfl_xor(a, o);
          b += __shfl_xor(b, o);
        }
        ps[m][i] = a;
        pq[m][i] = b;
      }
    if (sr == 0)
#pragma unroll
      for (int m = 0; m < 2; ++m)
#pragma unroll
        for (int i = 0; i < 4; ++i) {
          int row = m * 16 + g * 4 + i;
          red[row * 4 + wid] = ps[m][i];
          red[128 + row * 4 + wid] = pq[m][i];
        }
    __syncthreads();
    if (tid < 32) {
      float a = 0.f, b = 0.f;
#pragma unroll
      for (int w = 0; w < 4; ++w) {
        a += red[tid * 4 + w];
        b += red[128 + tid * 4 + w];
      }
      float mu = a * (1.f / 256.f);
      s_a[tid] = mu;
      s_b[tid] = rsqrtf(b * (1.f / 256.f) - mu * mu + 1e-5f);
    }
    __syncthreads();
#pragma unroll
    for (int m = 0; m < 2; ++m)
#pragma unroll
      for (int n = 0; n < 4; ++n)
#pragma unroll
        for (int i = 0; i < 4; ++i) {
          int row = m * 16 + g * 4 + i, col = wid * 64 + n * 16 + sr;
          dacc[m][n][i] =
              ((dacc[m][n][i] - s_a[row]) * s_b[row] * p1_lng[col] + p1_lnb[col]) * s_npm[row];
        }
  }

  // ---- P9: st1 = tanh(npm*(emb @ p2w1^T) + b1) -> B1 (din dead) ----
  {
    f32x4 acc[2][4] = {};
    mm_acc<128, E_S>(pool + E_O, w21, acc, wid, g, sr);
#pragma unroll
    for (int m = 0; m < 2; ++m)
#pragma unroll
      for (int n = 0; n < 4; ++n)
#pragma unroll
        for (int i = 0; i < 4; ++i) {
          int row = m * 16 + g * 4 + i, col = wid * 64 + n * 16 + sr;
          pool[B1_O + row * ACT_S + col] = bfb(tanh_f(s_npm[row] * acc[m][n][i] + p2_b1[col]));
        }
  }
  __syncthreads();

  // ---- P10: static = (st1 @ p2w2^T + b2)*npm -> sacc regs ----
  f32x4 sacc[2][4] = {};
  mm_acc<256, ACT_S>(pool + B1_O, w22, sacc, wid, g, sr);
#pragma unroll
  for (int m = 0; m < 2; ++m)
#pragma unroll
    for (int n = 0; n < 4; ++n)
#pragma unroll
      for (int i = 0; i < 4; ++i) {
        int row = m * 16 + g * 4 + i, col = wid * 64 + n * 16 + sr;
        sacc[m][n][i] = (sacc[m][n][i] + p2_b2[col]) * s_npm[row];
      }

  // ---- final: LN(dyn,lnc1), LN(sta,lnc2), (dyn-sta)^2 @ Wcls, sigmoid, masked mean ----
  {
    float* red = (float*)(pool + SC_O);
    float pd[2][4], qd[2][4], psx[2][4], qsx[2][4];
#pragma unroll
    for (int m = 0; m < 2; ++m)
#pragma unroll
      for (int i = 0; i < 4; ++i) {
        float a = 0.f, b = 0.f, c = 0.f, d = 0.f;
#pragma unroll
        for (int n = 0; n < 4; ++n) {
          float v = dacc[m][n][i], w = sacc[m][n][i];
          a += v;
          b += v * v;
          c += w;
          d += w * w;
        }
#pragma unroll
        for (int o = 1; o < 16; o <<= 1) {
          a += __shfl_xor(a, o);
          b += __shfl_xor(b, o);
          c += __shfl_xor(c, o);
          d += __shfl_xor(d, o);
        }
        pd[m][i] = a;
        qd[m][i] = b;
        psx[m][i] = c;
        qsx[m][i] = d;
      }
    __syncthreads();  // P8's red reads done on all waves before overwrite
    if (sr == 0)
#pragma unroll
      for (int m = 0; m < 2; ++m)
#pragma unroll
        for (int i = 0; i < 4; ++i) {
          int row = m * 16 + g * 4 + i;
          red[row * 4 + wid] = pd[m][i];
          red[128 + row * 4 + wid] = qd[m][i];
          red[256 + row * 4 + wid] = psx[m][i];
          red[384 + row * 4 + wid] = qsx[m][i];
        }
    __syncthreads();
    if (tid < 32) {
      float a = 0.f, b = 0.f, c = 0.f, d = 0.f;
#pragma unroll
      for (int w = 0; w < 4; ++w) {
        a += red[tid * 4 + w];
        b += red[128 + tid * 4 + w];
        c += red[256 + tid * 4 + w];
        d += red[384 + tid * 4 + w];
      }
      float muD = a * (1.f / 256.f), muS = c * (1.f / 256.f);
      s_a[tid] = muD;
      s_b[tid] = rsqrtf(b * (1.f / 256.f) - muD * muD + 1e-5f);
      s_c[tid] = muS;
      s_d[tid] = rsqrtf(d * (1.f / 256.f) - muS * muS + 1e-5f);
    }
    __syncthreads();
    float pp[2][4] = {};
#pragma unroll
    for (int m = 0; m < 2; ++m)
#pragma unroll
      for (int n = 0; n < 4; ++n)
#pragma unroll
        for (int i = 0; i < 4; ++i) {
          int row = m * 16 + g * 4 + i, col = wid * 64 + n * 16 + sr;
          float dn = (dacc[m][n][i] - s_a[row]) * s_b[row] * lnc1_g[col] + lnc1_b[col];
          float st = (sacc[m][n][i] - s_c[row]) * s_d[row] * lnc2_g[col] + lnc2_b[col];
          float df = dn - st;
          pp[m][i] = fmaf(df * df, Wcls[col], pp[m][i]);
        }
#pragma unroll
    for (int m = 0; m < 2; ++m)
#pragma unroll
      for (int i = 0; i < 4; ++i)
#pragma unroll
        for (int o = 1; o < 16; o <<= 1) pp[m][i] += __shfl_xor(pp[m][i], o);
    __syncthreads();
    if (sr == 0)
#pragma unroll
      for (int m = 0; m < 2; ++m)
#pragma unroll
        for (int i = 0; i < 4; ++i) red[(m * 16 + g * 4 + i) * 4 + wid] = pp[m][i];
    __syncthreads();
    if (tid < 32) {
      float s = red[tid * 4] + red[tid * 4 + 1] + red[tid * 4 + 2] + red[tid * 4 + 3] + bcls[0];
      s_prob[tid] = s_npm[tid] / (1.f + __expf(-s));
    }
    __syncthreads();
    if (tid < 2) {
      float psum = 0.f, nsum = 0.f;
#pragma unroll
      for (int r = 0; r < 16; ++r) {
        psum += s_prob[tid * 16 + r];
        nsum += s_npm[tid * 16 + r];
      }
      out[b0 + tid] = psum / nsum;
    }
  }
}

// ---- prep: fp32 weights -> bf16 (qkv pre-scaled by ln gammas) + (G,B) epilogue vectors ----
__global__ void prep_all(const float* __restrict__ Wq, const float* __restrict__ Wk,
                         const float* __restrict__ Wv, const float* __restrict__ Wfc1,
                         const float* __restrict__ p1w1, const float* __restrict__ p1w2,
                         const float* __restrict__ p2w1, const float* __restrict__ p2w2,
                         const float* __restrict__ g1, const float* __restrict__ b1,
                         const float* __restrict__ g2, const float* __restrict__ b2,
                         const float* __restrict__ g3, const float* __restrict__ b3,
                         u16* __restrict__ ws, float* __restrict__ aux) {
  int bx = blockIdx.x, t = threadIdx.x;
  if (bx >= 1536) {
    int m = bx - 1536;
    const float* W = (m == 0) ? Wq : (m == 1) ? Wk : Wv;
    const float* gg = (m == 0) ? g1 : (m == 1) ? g2 : g3;
    const float* bb = (m == 0) ? b1 : (m == 1) ? b2 : b3;
    float G = 0.f, Bv = 0.f;
    for (int k = 0; k < 128; ++k) {
      float w = W[t * 128 + k];
      G += w * gg[k];
      Bv += w * bb[k];
    }
    aux[m * 512 + t] = G;
    aux[m * 512 + 256 + t] = Bv;
    return;
  }
  const float* src;
  u16* dst;
  const float* sc = nullptr;
  int base;
  if (bx < 128) {
    src = Wq; dst = ws; sc = g1; base = bx;
  } else if (bx < 256) {
    src = Wk; dst = ws + 32768; sc = g2; base = bx - 128;
  } else if (bx < 384) {
    src = Wv; dst = ws + 65536; sc = g3; base = bx - 256;
  } else if (bx < 640) {
    src = Wfc1; dst = ws + 98304; base = bx - 384;
  } else if (bx < 896) {
    src = p1w1; dst = ws + 163840; base = bx - 640;
  } else if (bx < 1152) {
    src = p1w2; dst = ws + 229376; base = bx - 896;
  } else if (bx < 1280) {
    src = p2w1; dst = ws + 294912; base = bx - 1152;
  } else {
    src = p2w2; dst = ws + 327680; base = bx - 1280;
  }
  int i = base * 256 + t;
  float v = src[i];
  if (sc) v *= sc[i & 127];
  dst[i] = bfb(v);
}

extern "C" void kernel_launch(void* const* d_in, const int* in_sizes, int n_in,
                              void* d_out, int out_size, void* d_ws, size_t ws_size,
                              hipStream_t stream) {
  const int* x = (const int*)d_in[0];
  const float* node_emb = (const float*)d_in[1];
  const float* ln1_g = (const float*)d_in[2];
  const float* ln1_b = (const float*)d_in[3];
  const float* ln2_g = (const float*)d_in[4];
  const float* ln2_b = (const float*)d_in[5];
  const float* ln3_g = (const float*)d_in[6];
  const float* ln3_b = (const float*)d_in[7];
  const float* Wq = (const float*)d_in[8];
  const float* Wk = (const float*)d_in[9];
  const float* Wv = (const float*)d_in[10];
  const float* Wfc1 = (const float*)d_in[11];
  const float* p1_w1 = (const float*)d_in[12];
  const float* p1_b1 = (const float*)d_in[13];
  const float* p1_w2 = (const float*)d_in[14];
  const float* p1_b2 = (const float*)d_in[15];
  const float* p1_lng = (const float*)d_in[16];
  const float* p1_lnb = (const float*)d_in[17];
  const float* p2_w1 = (const float*)d_in[18];
  const float* p2_b1 = (const float*)d_in[19];
  const float* p2_w2 = (const float*)d_in[20];
  const float* p2_b2 = (const float*)d_in[21];
  const float* lnc1_g = (const float*)d_in[22];
  const float* lnc1_b = (const float*)d_in[23];
  const float* lnc2_g = (const float*)d_in[24];
  const float* lnc2_b = (const float*)d_in[25];
  const float* Wcls = (const float*)d_in[26];
  const float* bcls = (const float*)d_in[27];

  u16* ws = (u16*)d_ws;
  float* aux = (float*)(ws + 393216);

  prep_all<<<1539, 256, 0, stream>>>(Wq, Wk, Wv, Wfc1, p1_w1, p1_w2, p2_w1, p2_w2, ln1_g, ln1_b,
                                     ln2_g, ln2_b, ln3_g, ln3_b, ws, aux);

  const int B = in_sizes[0] / 16;
  fused_kernel<<<B / 2, 256, 0, stream>>>(
      x, node_emb, ws, ws + 32768, ws + 65536, ws + 98304, ws + 163840, ws + 229376, ws + 294912,
      ws + 327680, aux, p1_b1, p1_b2, p1_lng, p1_lnb, p2_b1, p2_b2, lnc1_g, lnc1_b, lnc2_g, lnc2_b,
      Wcls, bcls, (float*)d_out);
}